// Round 11
// baseline (155.798 us; speedup 1.0000x reference)
//
#include <hip/hip_runtime.h>

#define DIM 256
#define T_LEN 4096
#define K_CODES 1024
#define N_TOK 65536
#define NELEM 16777216

// ws layout (32-bit units):
//   [0,1024)        cnh2[k]  packed (bf16_hi | bf16_lo<<16) of 2+0.5|e|^2
//   [1024,1536)     loss partials (512 f32, one per fused block)
//   [4096,135168)   cbb: codebook bf16 row-major (512 KB)

typedef __attribute__((ext_vector_type(8))) short bf16x8;
typedef __attribute__((ext_vector_type(16))) float f32x16;

__device__ __forceinline__ unsigned short f2bf(float f) {     // RNE f32->bf16
    unsigned u = __builtin_bit_cast(unsigned, f);
    return (unsigned short)((u + 0x7FFFu + ((u >> 16) & 1u)) >> 16);
}
__device__ __forceinline__ float bf2f(unsigned short h) {
    return __builtin_bit_cast(float, (unsigned)h << 16);
}
__device__ __forceinline__ unsigned f2u(float f) { return __builtin_bit_cast(unsigned, f); }
__device__ __forceinline__ float u2f(unsigned u) { return __builtin_bit_cast(float, u); }
__device__ __forceinline__ unsigned umin2(unsigned a, unsigned b) { return a < b ? a : b; }

union FragU { bf16x8 v; unsigned short u[8]; unsigned w[4]; };

#define GLLOAD(gsrc, lbase)                                                              \
    __builtin_amdgcn_global_load_lds(                                                    \
        (const __attribute__((address_space(1))) unsigned int*)(gsrc),                   \
        (__attribute__((address_space(3))) unsigned int*)(lbase), 16, 0, 0)

// cvt two f32 -> packed bf16 pair, NEGATED (folds -x for the cn-fold trick), RNE.
__device__ __forceinline__ unsigned cvtpk_neg(float a, float b) {
    unsigned r;
    asm("v_cvt_pk_bf16_f32 %0, -%1, -%2" : "=v"(r) : "v"(a), "v"(b));
    return r;
}

// ---------------- prep: cb->bf16 (row-major), cnh2 split pair ----------------
__global__ __launch_bounds__(256) void prep(const float* __restrict__ cb,
                                            unsigned short* __restrict__ cbb,
                                            unsigned* __restrict__ cnh2) {
    const int k = blockIdx.x * 4 + (threadIdx.x >> 6);
    const int lane = threadIdx.x & 63;
    float4 v = *reinterpret_cast<const float4*>(cb + (size_t)k * DIM + lane * 4);
    float s = v.x * v.x + v.y * v.y + v.z * v.z + v.w * v.w;
    #pragma unroll
    for (int off = 32; off; off >>= 1) s += __shfl_down(s, off);
    if (lane == 0) {
        float cn = 2.0f + 0.5f * s;
        unsigned short chi = f2bf(cn);
        unsigned short clo = f2bf(cn - bf2f(chi));
        cnh2[k] = (unsigned)chi | ((unsigned)clo << 16);
    }
    ushort4 o;
    o.x = f2bf(v.x); o.y = f2bf(v.y); o.z = f2bf(v.z); o.w = f2bf(v.w);
    *reinterpret_cast<ushort4*>(cbb + (size_t)k * DIM + lane * 4) = o;
}

// ---------------- fused: argmin sweep (K-quarters) + scatter + loss ----------------
// 512 blocks x 512 thr (8 waves = 2 token-groups x 4 K-quarters) -> 2 blocks/CU,
// 16 waves/CU = 4 waves/SIMD. Ring = 64 KB: x-ingest tile, then 4x16KB chunk
// slots (wave q reads only slot q -> per-wave LDS reads halve vs r9), then f32
// scatter tile. 8 rounds; stage all 4 slots per round (single-buffered; drain
// covered by the co-resident block + post-barrier epilogue).
__global__ __launch_bounds__(512, 4) void vq_fused(const float* __restrict__ x,
                                                   const unsigned short* __restrict__ cbb,
                                                   const unsigned* __restrict__ cnh2,
                                                   const float* __restrict__ cbf,
                                                   float* __restrict__ out,
                                                   float* __restrict__ part) {
    __shared__ __align__(16) unsigned short ring[4][8192];   // 64 KB multi-use
    __shared__ unsigned cnl[1024];                           // 4 KB
    __shared__ unsigned kbx[8][64];                          // 2 KB key exchange
    __shared__ int kkl[128];                                 // merged codes
    __shared__ float wsum[8];
    const int tid = threadIdx.x;
    const int w = tid >> 6, lane = tid & 63, hi = lane >> 5, ln31 = lane & 31;
    const int tg = w >> 2;                    // token group (0,1): 64 tokens each
    const int q = w & 3;                      // codebook quarter (0..3)
    const int tw0 = blockIdx.x * 128;
    const int b = tw0 >> 12, tb = tw0 & (T_LEN - 1);
    char* ldsb = (char*)&ring[0][0];

    cnl[tid] = cnh2[tid];
    cnl[tid + 512] = cnh2[tid + 512];

    // ---- x ingest: [128 t][128 c] bf16 tile per c-half, half h -> ring + h*32KB ----
    const int tqi = tid & 31, cqi = tid >> 5;               // cqi 0..15
    const float* xb = x + (size_t)b * DIM * T_LEN + tb + 4 * tqi;
    const int wswz = (tqi & 7) << 4;
    float x2s = 0.0f;

    #pragma unroll
    for (int h = 0; h < 2; ++h) {
        char* lds = ldsb + h * 32768;
        #pragma unroll
        for (int ii = 0; ii < 2; ++ii) {
            const int cl = (ii * 16 + cqi) * 4;             // c within half (0..124)
            const float* p = xb + (size_t)(h * 128 + cl) * T_LEN;
            const float4 P0 = *reinterpret_cast<const float4*>(p);
            const float4 P1 = *reinterpret_cast<const float4*>(p + T_LEN);
            const float4 P2 = *reinterpret_cast<const float4*>(p + 2 * T_LEN);
            const float4 P3 = *reinterpret_cast<const float4*>(p + 3 * T_LEN);
            x2s = fmaf(P0.x, P0.x, fmaf(P0.y, P0.y, fmaf(P0.z, P0.z, fmaf(P0.w, P0.w, x2s))));
            x2s = fmaf(P1.x, P1.x, fmaf(P1.y, P1.y, fmaf(P1.z, P1.z, fmaf(P1.w, P1.w, x2s))));
            x2s = fmaf(P2.x, P2.x, fmaf(P2.y, P2.y, fmaf(P2.z, P2.z, fmaf(P2.w, P2.w, x2s))));
            x2s = fmaf(P3.x, P3.x, fmaf(P3.y, P3.y, fmaf(P3.z, P3.z, fmaf(P3.w, P3.w, x2s))));
            const unsigned l0 = cvtpk_neg(P0.x, P0.y), h0 = cvtpk_neg(P0.z, P0.w);
            const unsigned l1 = cvtpk_neg(P1.x, P1.y), h1 = cvtpk_neg(P1.z, P1.w);
            const unsigned l2 = cvtpk_neg(P2.x, P2.y), h2 = cvtpk_neg(P2.z, P2.w);
            const unsigned l3 = cvtpk_neg(P3.x, P3.y), h3 = cvtpk_neg(P3.z, P3.w);
            const unsigned q0a = __builtin_amdgcn_perm(l1, l0, 0x05040100u);
            const unsigned q0b = __builtin_amdgcn_perm(h1, h0, 0x05040100u);
            const unsigned q1a = __builtin_amdgcn_perm(l1, l0, 0x07060302u);
            const unsigned q1b = __builtin_amdgcn_perm(h1, h0, 0x07060302u);
            const unsigned q2a = __builtin_amdgcn_perm(l3, l2, 0x05040100u);
            const unsigned q2b = __builtin_amdgcn_perm(h3, h2, 0x05040100u);
            const unsigned q3a = __builtin_amdgcn_perm(l3, l2, 0x07060302u);
            const unsigned q3b = __builtin_amdgcn_perm(h3, h2, 0x07060302u);
            const int t4 = 4 * tqi, cb2 = cl * 2;
            uint2 u;
            u.x = q0a; u.y = q0b;
            *reinterpret_cast<uint2*>(lds + ((((t4 + 0) << 8) + cb2) ^ wswz)) = u;
            u.x = q1a; u.y = q1b;
            *reinterpret_cast<uint2*>(lds + ((((t4 + 1) << 8) + cb2) ^ wswz)) = u;
            u.x = q2a; u.y = q2b;
            *reinterpret_cast<uint2*>(lds + ((((t4 + 2) << 8) + cb2) ^ wswz)) = u;
            u.x = q3a; u.y = q3b;
            *reinterpret_cast<uint2*>(lds + ((((t4 + 3) << 8) + cb2) ^ wswz)) = u;
        }
    }
    __syncthreads();
    FragU xf[2][16];                    // NEGATED bf16 frags: this tg's 64 tokens
    #pragma unroll
    for (int g = 0; g < 2; ++g) {
        const int tp = tg * 64 + g * 32 + ln31;
        const int rswz = ((tp >> 2) & 7) << 4;
        #pragma unroll
        for (int h = 0; h < 2; ++h) {
            #pragma unroll
            for (int cf = 0; cf < 8; ++cf) {
                int ad = (tp << 8) + cf * 32 + hi * 16;
                xf[g][h * 8 + cf].v =
                    *reinterpret_cast<const bf16x8*>(ldsb + h * 32768 + (ad ^ rswz));
            }
        }
    }
    __syncthreads();   // frag ds_reads drained -> ring reusable as chunk slots

    // ---- staging: round r = chunks 4r..4r+3 -> slots 0..3 (64 KB, linear dest,
    //      pre-swizzled source; 8 loads/thread) ----
    auto stage = [&](int r) {
        #pragma unroll
        for (int j = 0; j < 8; ++j) {
            const int o = j * 8192 + tid * 16;
            const int oc = o & 16383;
            const int so = r * 65536 + (o & ~16383) + (oc ^ (((oc >> 9) & 31) << 4));
            GLLOAD((const char*)cbb + so, ldsb + j * 8192 + w * 1024);
        }
    };
    stage(0);

    FragU onef;                                   // B-const: k=0,1 -> 1.0
    #pragma unroll
    for (int i = 0; i < 8; ++i) onef.u[i] = (hi == 0 && i < 2) ? 0x3F80 : 0;

    unsigned b0a = 0xFFFFFFFFu, b0b = 0xFFFFFFFFu;   // acc0 chains
    unsigned b1a = 0xFFFFFFFFu, b1b = 0xFFFFFFFFu;   // acc1 chains
    const char* cbp = ldsb + q * 16384;              // this wave's slot
    const int rbase = ln31 * 512;

    for (int ir = 0; ir < 8; ++ir) {
        asm volatile("s_waitcnt vmcnt(0)" ::: "memory");   // this round's slots landed
        __builtin_amdgcn_s_barrier();
        __builtin_amdgcn_sched_barrier(0);

        const int ci = ir * 4 + q;                   // this wave's 32-code chunk
        const unsigned d = cnl[ci * 32 + ln31];
        FragU cfr;
        cfr.u[0] = hi ? (unsigned short)0 : (unsigned short)(d & 0xFFFFu);
        cfr.u[1] = hi ? (unsigned short)0 : (unsigned short)(d >> 16);
        #pragma unroll
        for (int i = 2; i < 8; ++i) cfr.u[i] = 0;

        f32x16 acc0, acc1;
        #pragma unroll
        for (int i = 0; i < 16; ++i) { acc0[i] = 0.0f; acc1[i] = 0.0f; }
        acc0 = __builtin_amdgcn_mfma_f32_32x32x16_bf16(cfr.v, onef.v, acc0, 0, 0, 0);
        acc1 = __builtin_amdgcn_mfma_f32_32x32x16_bf16(cfr.v, onef.v, acc1, 0, 0, 0);

        #pragma unroll
        for (int hf = 0; hf < 2; ++hf) {            // two 8-frag halves: af reuse
            bf16x8 af[8];
            #pragma unroll
            for (int cf = 0; cf < 8; ++cf) {
                const int cbyte = (hf * 8 + cf) * 32 + hi * 16;
                af[cf] = *(const bf16x8*)(cbp + rbase + (cbyte ^ (ln31 << 4)));
            }
            #pragma unroll
            for (int cf = 0; cf < 8; ++cf) {
                acc0 = __builtin_amdgcn_mfma_f32_32x32x16_bf16(af[cf], xf[0][hf * 8 + cf].v, acc0, 0, 0, 0);
                acc1 = __builtin_amdgcn_mfma_f32_32x32x16_bf16(af[cf], xf[1][hf * 8 + cf].v, acc1, 0, 0, 0);
            }
        }

        __builtin_amdgcn_s_barrier();               // all waves' slot reads consumed
        __builtin_amdgcn_sched_barrier(0);
        if (ir < 7) stage(ir + 1);                  // overwrite slots; drain next round

        // epilogue AFTER the barrier+stage issue: overlaps the staging drain
        const int kbl = ci * 32 + hi * 4;
        #pragma unroll
        for (int rg = 0; rg < 16; ++rg) {
            const unsigned kk = (unsigned)(kbl + (rg & 3) + 8 * (rg >> 2));
            const unsigned p0 = (f2u(acc0[rg]) & 0xFFFFFC00u) | kk;
            const unsigned p1 = (f2u(acc1[rg]) & 0xFFFFFC00u) | kk;
            if (rg & 1) { b0b = umin2(b0b, p0); b1b = umin2(b1b, p1); }
            else        { b0a = umin2(b0a, p0); b1a = umin2(b1a, p1); }
        }
    }

    // merge chains + hi-halves (disjoint code subsets, same tokens)
    unsigned best0 = umin2(b0a, b0b);
    unsigned best1 = umin2(b1a, b1b);
    best0 = umin2(best0, __shfl_xor(best0, 32));
    best1 = umin2(best1, __shfl_xor(best1, 32));
    if (hi == 0) { kbx[w][ln31] = best0; kbx[w][32 + ln31] = best1; }
    __syncthreads();

    // merge K-quarters; loss partial
    float red = x2s;
    if (tid < 128) {
        const int tgn = tid >> 6, tt = tid & 63;
        unsigned key = umin2(umin2(kbx[tgn * 4 + 0][tt], kbx[tgn * 4 + 1][tt]),
                             umin2(kbx[tgn * 4 + 2][tt], kbx[tgn * 4 + 3][tt]));
        kkl[tid] = (int)(key & 1023u);
        red += 2.0f * (u2f(key & 0xFFFFFC00u) - 2.0f);
    }
    #pragma unroll
    for (int off = 32; off; off >>= 1) red += __shfl_down(red, off);
    if (lane == 0) wsum[w] = red;
    __syncthreads();
    if (tid == 0) {
        float s = 0.0f;
        #pragma unroll
        for (int i = 0; i < 8; ++i) s += wsum[i];
        part[blockIdx.x] = s;
    }

    // ---- fused scatter: gather fp32 rows (L2) -> LDS transpose -> coalesced out ----
    float* fs = (float*)ldsb;                      // [64 c][132 t] f32 = 33.8 KB
    const int tt = tid & 127, ch = tid >> 7;       // 4 threads per token
    const size_t rowb = (size_t)kkl[tt] * DIM;
    const int cw = tid >> 3, th = tid & 7;         // write mapping
    #pragma unroll 1
    for (int sl = 0; sl < 4; ++sl) {
        float4 g[4];
        #pragma unroll
        for (int i = 0; i < 4; ++i)
            g[i] = *reinterpret_cast<const float4*>(cbf + rowb + sl * 64 + ch * 16 + 4 * i);
        __syncthreads();                           // prev slice reads done
        #pragma unroll
        for (int i = 0; i < 4; ++i) {
            const int c0 = ch * 16 + 4 * i;
            fs[(c0 + 0) * 132 + tt] = g[i].x;
            fs[(c0 + 1) * 132 + tt] = g[i].y;
            fs[(c0 + 2) * 132 + tt] = g[i].z;
            fs[(c0 + 3) * 132 + tt] = g[i].w;
        }
        __syncthreads();
        #pragma unroll
        for (int p = 0; p < 4; ++p) {
            const int t0 = p * 32 + th * 4;
            const float4 v = *reinterpret_cast<const float4*>(fs + cw * 132 + t0);
            *reinterpret_cast<float4*>(
                out + (((size_t)(b * DIM + sl * 64 + cw)) << 12) + tb + t0) = v;
        }
    }
}

// ---------------- finalize loss ----------------
__global__ __launch_bounds__(256) void finalize(const float* __restrict__ part,
                                                float* __restrict__ loss_out) {
    double s = (double)part[threadIdx.x] + (double)part[threadIdx.x + 256];
    #pragma unroll
    for (int off = 32; off; off >>= 1) s += __shfl_down(s, off);
    __shared__ double wsum[4];
    const int lane = threadIdx.x & 63, wv = threadIdx.x >> 6;
    if (lane == 0) wsum[wv] = s;
    __syncthreads();
    if (threadIdx.x == 0)
        *loss_out = (float)(2.0 * (wsum[0] + wsum[1] + wsum[2] + wsum[3]) / (double)NELEM);
}

extern "C" void kernel_launch(void* const* d_in, const int* in_sizes, int n_in,
                              void* d_out, int out_size, void* d_ws, size_t ws_size,
                              hipStream_t stream) {
    const float* x  = (const float*)d_in[0];    // [16,256,4096]
    const float* cb = (const float*)d_in[1];    // [1024,256]
    float* out = (float*)d_out;                 // quant (16777216) + loss (1)
    unsigned* ws = (unsigned*)d_ws;
    unsigned* cnh2 = ws;                        // 1024 u32
    float* part = (float*)(ws + 1024);          // 512 f32
    unsigned short* cbb = (unsigned short*)(ws + 4096);  // 512 KB bf16 codebook

    prep<<<K_CODES / 4, 256, 0, stream>>>(cb, cbb, cnh2);
    vq_fused<<<N_TOK / 128, 512, 0, stream>>>(x, cbb, cnh2, cb, out, part);
    finalize<<<1, 256, 0, stream>>>(part, out + NELEM);
}

// Round 12
// 67.311 us; speedup vs baseline: 2.3146x; 2.3146x over previous
//
#include <hip/hip_runtime.h>

#define DIM 256
#define T_LEN 4096
#define K_CODES 1024
#define N_TOK 65536
#define NELEM 16777216

// ws layout (32-bit units):
//   [0,1024)        cnh2[k]  packed (bf16_hi | bf16_lo<<16) of 2+0.5|e|^2
//   [1024,2048)     loss partials (1024 f32, one per fused block)
//   [4096,135168)   cbb: codebook bf16 row-major (512 KB)

typedef __attribute__((ext_vector_type(8))) short bf16x8;
typedef __attribute__((ext_vector_type(4))) float f32x4;

__device__ __forceinline__ unsigned short f2bf(float f) {     // RNE f32->bf16
    unsigned u = __builtin_bit_cast(unsigned, f);
    return (unsigned short)((u + 0x7FFFu + ((u >> 16) & 1u)) >> 16);
}
__device__ __forceinline__ float bf2f(unsigned short h) {
    return __builtin_bit_cast(float, (unsigned)h << 16);
}
__device__ __forceinline__ unsigned f2u(float f) { return __builtin_bit_cast(unsigned, f); }
__device__ __forceinline__ float u2f(unsigned u) { return __builtin_bit_cast(float, u); }
__device__ __forceinline__ unsigned umin2(unsigned a, unsigned b) { return a < b ? a : b; }

union FragU { bf16x8 v; unsigned short u[8]; unsigned w[4]; };

#define GLLOAD(gsrc, lbase)                                                              \
    __builtin_amdgcn_global_load_lds(                                                    \
        (const __attribute__((address_space(1))) unsigned int*)(gsrc),                   \
        (__attribute__((address_space(3))) unsigned int*)(lbase), 16, 0, 0)

// cvt two f32 -> packed bf16 pair, NEGATED (folds -x for the cn-fold trick), RNE.
__device__ __forceinline__ unsigned cvtpk_neg(float a, float b) {
    unsigned r;
    asm("v_cvt_pk_bf16_f32 %0, -%1, -%2" : "=v"(r) : "v"(a), "v"(b));
    return r;
}

// ---------------- prep: cb->bf16 (row-major), cnh2 split pair ----------------
__global__ __launch_bounds__(256) void prep(const float* __restrict__ cb,
                                            unsigned short* __restrict__ cbb,
                                            unsigned* __restrict__ cnh2) {
    const int k = blockIdx.x * 4 + (threadIdx.x >> 6);
    const int lane = threadIdx.x & 63;
    float4 v = *reinterpret_cast<const float4*>(cb + (size_t)k * DIM + lane * 4);
    float s = v.x * v.x + v.y * v.y + v.z * v.z + v.w * v.w;
    #pragma unroll
    for (int off = 32; off; off >>= 1) s += __shfl_down(s, off);
    if (lane == 0) {
        float cn = 2.0f + 0.5f * s;
        unsigned short chi = f2bf(cn);
        unsigned short clo = f2bf(cn - bf2f(chi));
        cnh2[k] = (unsigned)chi | ((unsigned)clo << 16);
    }
    ushort4 o;
    o.x = f2bf(v.x); o.y = f2bf(v.y); o.z = f2bf(v.z); o.w = f2bf(v.w);
    *reinterpret_cast<ushort4*>(cbb + (size_t)k * DIM + lane * 4) = o;
}

// chunk-internal swizzle: row r (16 codes/chunk), spreads a 16B read across 32 banks
__device__ __forceinline__ int swz16(int r) {
    return ((r & 15) << 4) | ((r & 1) << 8);
}

// ---------------- fused: argmin (16x16x32 MFMA, K-halves) + scatter + loss ----------------
// 1024 blocks x 256 thr (4 waves = 2 tg x 2 kh), 32 tokens/wave -> xf fits in 64
// VGPR -> <=128 regs/wave -> 4 blocks/CU = 16 waves/CU = 4 waves/SIMD.
// LDS ~37.6 KB: 2x16KB chunk dbuf (also x-ingest + scatter scratch) + cnl 4KB.
// 32 rounds of 16 codes/half; counted vmcnt(4) + raw barriers (r8-proven).
__global__ __launch_bounds__(256, 4) void vq_fused(const float* __restrict__ x,
                                                   const unsigned short* __restrict__ cbb,
                                                   const unsigned* __restrict__ cnh2,
                                                   const float* __restrict__ cbf,
                                                   float* __restrict__ out,
                                                   float* __restrict__ part) {
    __shared__ __align__(16) unsigned short ring[2][8192];   // 2 x 16 KB
    __shared__ unsigned cnl[1024];                           // 4 KB
    __shared__ unsigned kbx[4][32];                          // key exchange
    __shared__ int kkl[64];                                  // merged codes
    __shared__ float wsum[4];
    const int tid = threadIdx.x;
    const int w = tid >> 6, lane = tid & 63, hi4 = lane >> 4, ln15 = lane & 15;
    const int tg = w >> 1;                    // token group (0,1): 32 tokens each
    const int kh = w & 1;                     // codebook half (0,1)
    const int tw0 = blockIdx.x * 64;
    const int b = tw0 >> 12, tb = tw0 & (T_LEN - 1);
    char* ldsb = (char*)&ring[0][0];

    cnl[tid] = cnh2[tid];
    cnl[tid + 256] = cnh2[tid + 256];
    cnl[tid + 512] = cnh2[tid + 512];
    cnl[tid + 768] = cnh2[tid + 768];

    // ---- x ingest: [64 t][128 c] bf16 tile per c-half -> ldsb + h*16KB ----
    const int tqi = tid & 15, cqi = tid >> 4;               // t-quad (16), c-quad (16)
    const float* xb = x + (size_t)b * DIM * T_LEN + tb + 4 * tqi;
    const int wswz = (tqi & 7) << 4;
    float x2s = 0.0f;

    #pragma unroll
    for (int h = 0; h < 2; ++h) {
        char* lds = ldsb + h * 16384;
        #pragma unroll
        for (int ii = 0; ii < 2; ++ii) {
            const int cl = (ii * 16 + cqi) * 4;             // c within half (0..124)
            const float* p = xb + (size_t)(h * 128 + cl) * T_LEN;
            const float4 P0 = *reinterpret_cast<const float4*>(p);
            const float4 P1 = *reinterpret_cast<const float4*>(p + T_LEN);
            const float4 P2 = *reinterpret_cast<const float4*>(p + 2 * T_LEN);
            const float4 P3 = *reinterpret_cast<const float4*>(p + 3 * T_LEN);
            x2s = fmaf(P0.x, P0.x, fmaf(P0.y, P0.y, fmaf(P0.z, P0.z, fmaf(P0.w, P0.w, x2s))));
            x2s = fmaf(P1.x, P1.x, fmaf(P1.y, P1.y, fmaf(P1.z, P1.z, fmaf(P1.w, P1.w, x2s))));
            x2s = fmaf(P2.x, P2.x, fmaf(P2.y, P2.y, fmaf(P2.z, P2.z, fmaf(P2.w, P2.w, x2s))));
            x2s = fmaf(P3.x, P3.x, fmaf(P3.y, P3.y, fmaf(P3.z, P3.z, fmaf(P3.w, P3.w, x2s))));
            const unsigned l0 = cvtpk_neg(P0.x, P0.y), h0 = cvtpk_neg(P0.z, P0.w);
            const unsigned l1 = cvtpk_neg(P1.x, P1.y), h1 = cvtpk_neg(P1.z, P1.w);
            const unsigned l2 = cvtpk_neg(P2.x, P2.y), h2 = cvtpk_neg(P2.z, P2.w);
            const unsigned l3 = cvtpk_neg(P3.x, P3.y), h3 = cvtpk_neg(P3.z, P3.w);
            const unsigned q0a = __builtin_amdgcn_perm(l1, l0, 0x05040100u);
            const unsigned q0b = __builtin_amdgcn_perm(h1, h0, 0x05040100u);
            const unsigned q1a = __builtin_amdgcn_perm(l1, l0, 0x07060302u);
            const unsigned q1b = __builtin_amdgcn_perm(h1, h0, 0x07060302u);
            const unsigned q2a = __builtin_amdgcn_perm(l3, l2, 0x05040100u);
            const unsigned q2b = __builtin_amdgcn_perm(h3, h2, 0x05040100u);
            const unsigned q3a = __builtin_amdgcn_perm(l3, l2, 0x07060302u);
            const unsigned q3b = __builtin_amdgcn_perm(h3, h2, 0x07060302u);
            const int t4 = 4 * tqi, cb2 = cl * 2;
            uint2 u;
            u.x = q0a; u.y = q0b;
            *reinterpret_cast<uint2*>(lds + ((((t4 + 0) << 8) + cb2) ^ wswz)) = u;
            u.x = q1a; u.y = q1b;
            *reinterpret_cast<uint2*>(lds + ((((t4 + 1) << 8) + cb2) ^ wswz)) = u;
            u.x = q2a; u.y = q2b;
            *reinterpret_cast<uint2*>(lds + ((((t4 + 2) << 8) + cb2) ^ wswz)) = u;
            u.x = q3a; u.y = q3b;
            *reinterpret_cast<uint2*>(lds + ((((t4 + 3) << 8) + cb2) ^ wswz)) = u;
        }
    }
    __syncthreads();
    FragU xf[2][8];             // NEGATED bf16 B-frags: [token tile][kblock]; 64 VGPR
    #pragma unroll
    for (int tt = 0; tt < 2; ++tt) {
        const int tp = tg * 32 + tt * 16 + ln15;
        const int rswz = ((tp >> 2) & 7) << 4;
        #pragma unroll
        for (int h = 0; h < 2; ++h) {
            #pragma unroll
            for (int kb = 0; kb < 4; ++kb) {
                int ad = h * 16384 + (tp << 8) + kb * 64 + hi4 * 16;
                xf[tt][h * 4 + kb].v = *reinterpret_cast<const bf16x8*>(ldsb + (ad ^ rswz));
            }
        }
    }
    __syncthreads();            // ring free for chunk staging

    // ---- staging: round ci = both halves' 16-code chunks (16 KB) into ring[buf].
    //      Linear LDS dest; source pre-swizzled with swz16 (involution). ----
    auto stage = [&](int ci, int buf) {
        char* lb = (char*)&ring[buf][0] + w * 4096;
        #pragma unroll
        for (int j = 0; j < 4; ++j) {
            const int o = w * 4096 + j * 1024 + lane * 16;   // 0..16383
            const int kh2 = o >> 13;
            const int oh = o & 8191;
            const int so = kh2 * 262144 + ci * 8192 + (oh ^ swz16(oh >> 9));
            GLLOAD((const char*)cbb + so, lb + j * 1024);
        }
    };
    stage(0, 0);

    FragU onef;                 // B-const: k=0,1 -> 1.0 (lanes hi4==0)
    #pragma unroll
    for (int i = 0; i < 8; ++i) onef.u[i] = (hi4 == 0 && i < 2) ? 0x3F80 : 0;

    unsigned best0 = 0xFFFFFFFFu, best1 = 0xFFFFFFFFu;
    const int rswzr = swz16(ln15);

    for (int ci = 0; ci < 32; ++ci) {
        const int cur = ci & 1;
        if (ci < 31) {
            stage(ci + 1, cur ^ 1);
            asm volatile("s_waitcnt vmcnt(4)" ::: "memory");   // round ci landed
        } else {
            asm volatile("s_waitcnt vmcnt(0)" ::: "memory");
        }
        __builtin_amdgcn_s_barrier();
        __builtin_amdgcn_sched_barrier(0);

        const char* cbp = (const char*)&ring[cur][0] + kh * 8192 + ln15 * 512;
        const unsigned d = cnl[kh * 512 + ci * 16 + ln15];
        FragU cfr;
        cfr.u[0] = (hi4 == 0) ? (unsigned short)(d & 0xFFFFu) : (unsigned short)0;
        cfr.u[1] = (hi4 == 0) ? (unsigned short)(d >> 16) : (unsigned short)0;
        #pragma unroll
        for (int i = 2; i < 8; ++i) cfr.u[i] = 0;

        f32x4 acc0 = {0.0f, 0.0f, 0.0f, 0.0f};
        f32x4 acc1 = {0.0f, 0.0f, 0.0f, 0.0f};
        acc0 = __builtin_amdgcn_mfma_f32_16x16x32_bf16(cfr.v, onef.v, acc0, 0, 0, 0);
        acc1 = __builtin_amdgcn_mfma_f32_16x16x32_bf16(cfr.v, onef.v, acc1, 0, 0, 0);

        #pragma unroll
        for (int hf = 0; hf < 2; ++hf) {            // af[4] at a time (reg pressure)
            bf16x8 af[4];
            #pragma unroll
            for (int kb = 0; kb < 4; ++kb) {
                const int cbyte = (hf * 4 + kb) * 64 + hi4 * 16;
                af[kb] = *(const bf16x8*)(cbp + (cbyte ^ rswzr));
            }
            #pragma unroll
            for (int kb = 0; kb < 4; ++kb) {
                acc0 = __builtin_amdgcn_mfma_f32_16x16x32_bf16(af[kb], xf[0][hf * 4 + kb].v, acc0, 0, 0, 0);
                acc1 = __builtin_amdgcn_mfma_f32_16x16x32_bf16(af[kb], xf[1][hf * 4 + kb].v, acc1, 0, 0, 0);
            }
        }

        // C layout 16x16: col=lane&15 (token), row=hi4*4+rg (code within chunk)
        const int kbl = kh * 512 + ci * 16 + hi4 * 4;
        #pragma unroll
        for (int rg = 0; rg < 4; ++rg) {
            const unsigned kk = (unsigned)(kbl + rg);
            best0 = umin2(best0, (f2u(acc0[rg]) & 0xFFFFFC00u) | kk);
            best1 = umin2(best1, (f2u(acc1[rg]) & 0xFFFFFC00u) | kk);
        }
        __builtin_amdgcn_s_barrier();
        __builtin_amdgcn_sched_barrier(0);
    }

    // reduce over the 4 row-groups (lanes l, l^16, l^32, l^48 share a token col)
    best0 = umin2(best0, __shfl_xor(best0, 16));
    best0 = umin2(best0, __shfl_xor(best0, 32));
    best1 = umin2(best1, __shfl_xor(best1, 16));
    best1 = umin2(best1, __shfl_xor(best1, 32));
    if (lane < 16) {
        kbx[w][lane] = best0;          // token tg*32 + lane
        kbx[w][16 + lane] = best1;     // token tg*32 + 16 + lane
    }
    __syncthreads();

    // merge K-halves; write kkl + loss partial
    float red = x2s;
    if (tid < 64) {
        const int tgn = tid >> 5, i32 = tid & 31;
        const unsigned key = umin2(kbx[tgn * 2][i32], kbx[tgn * 2 + 1][i32]);
        kkl[tid] = (int)(key & 1023u);
        red += 2.0f * (u2f(key & 0xFFFFFC00u) - 2.0f);
    }
    #pragma unroll
    for (int off = 32; off; off >>= 1) red += __shfl_down(red, off);
    if (lane == 0) wsum[w] = red;
    __syncthreads();
    if (tid == 0) part[blockIdx.x] = wsum[0] + wsum[1] + wsum[2] + wsum[3];

    // ---- fused scatter: gather fp32 rows (L2) -> LDS transpose -> coalesced out ----
    float* fs = (float*)ldsb;                      // [64 c][68 t] f32 = 17.4 KB
    const int tt = tid & 63, ch = tid >> 6;        // 4 threads per token (16 c each)
    const size_t rowb = (size_t)kkl[tt] * DIM;
    #pragma unroll 1
    for (int sl = 0; sl < 4; ++sl) {
        float4 g[4];
        #pragma unroll
        for (int i = 0; i < 4; ++i)
            g[i] = *reinterpret_cast<const float4*>(cbf + rowb + sl * 64 + ch * 16 + 4 * i);
        __syncthreads();                           // prev slice reads done
        #pragma unroll
        for (int i = 0; i < 4; ++i) {
            const int c0 = ch * 16 + 4 * i;
            fs[(c0 + 0) * 68 + tt] = g[i].x;
            fs[(c0 + 1) * 68 + tt] = g[i].y;
            fs[(c0 + 2) * 68 + tt] = g[i].z;
            fs[(c0 + 3) * 68 + tt] = g[i].w;
        }
        __syncthreads();
        #pragma unroll
        for (int p = 0; p < 2; ++p) {              // 128-byte write runs
            const int c = p * 32 + (tid >> 3), th = tid & 7;
            #pragma unroll
            for (int q = 0; q < 2; ++q) {
                const int t4 = (q * 8 + th) * 4;
                const float4 v = *reinterpret_cast<const float4*>(fs + c * 68 + t4);
                *reinterpret_cast<float4*>(
                    out + (((size_t)(b * DIM + sl * 64 + c)) << 12) + tb + t4) = v;
            }
        }
    }
}

// ---------------- finalize loss ----------------
__global__ __launch_bounds__(256) void finalize(const float* __restrict__ part,
                                                float* __restrict__ loss_out) {
    double s = (double)part[threadIdx.x] + (double)part[threadIdx.x + 256]
             + (double)part[threadIdx.x + 512] + (double)part[threadIdx.x + 768];
    #pragma unroll
    for (int off = 32; off; off >>= 1) s += __shfl_down(s, off);
    __shared__ double wsum[4];
    const int lane = threadIdx.x & 63, wv = threadIdx.x >> 6;
    if (lane == 0) wsum[wv] = s;
    __syncthreads();
    if (threadIdx.x == 0)
        *loss_out = (float)(2.0 * (wsum[0] + wsum[1] + wsum[2] + wsum[3]) / (double)NELEM);
}

extern "C" void kernel_launch(void* const* d_in, const int* in_sizes, int n_in,
                              void* d_out, int out_size, void* d_ws, size_t ws_size,
                              hipStream_t stream) {
    const float* x  = (const float*)d_in[0];    // [16,256,4096]
    const float* cb = (const float*)d_in[1];    // [1024,256]
    float* out = (float*)d_out;                 // quant (16777216) + loss (1)
    unsigned* ws = (unsigned*)d_ws;
    unsigned* cnh2 = ws;                        // 1024 u32
    float* part = (float*)(ws + 1024);          // 1024 f32
    unsigned short* cbb = (unsigned short*)(ws + 4096);  // 512 KB bf16 codebook

    prep<<<K_CODES / 4, 256, 0, stream>>>(cb, cbb, cnh2);
    vq_fused<<<N_TOK / 64, 256, 0, stream>>>(x, cbb, cnh2, cb, out, part);
    finalize<<<1, 256, 0, stream>>>(part, out + NELEM);
}

// Round 13
// 57.348 us; speedup vs baseline: 2.7167x; 1.1737x over previous
//
#include <hip/hip_runtime.h>

#define DIM 256
#define T_LEN 4096
#define K_CODES 1024
#define N_TOK 65536
#define NELEM 16777216

// ws layout (32-bit units):
//   [0,1024)       cnh2[k] packed (bf16_hi | bf16_lo<<16) of 128 + 128*|e_k|^2
//   [1024,1536)    loss partials (512 f32)
//   [4096,69632)   cbb8: fp8(256*cb), chunk-tiled 256 KB:
//                  byte = ci*8192 + hi*4096 + q*512 + r*16 + p
//                  code k = ci*32+r; dim d: q=d>>5, rem=d&31, hi=(rem>>3)&1,
//                  p = (rem&7) + ((rem>>4)<<3)
// Score: s' = 128 + 128|e|^2 - 256*(e_fp8 . x_fp8)  in ~[80,180] > 0.

typedef __attribute__((ext_vector_type(8))) short bf16x8;
typedef __attribute__((ext_vector_type(16))) float f32x16;
typedef __attribute__((ext_vector_type(2))) long long2x;

__device__ __forceinline__ unsigned short f2bf(float f) {     // RNE f32->bf16
    unsigned u = __builtin_bit_cast(unsigned, f);
    return (unsigned short)((u + 0x7FFFu + ((u >> 16) & 1u)) >> 16);
}
__device__ __forceinline__ float bf2f(unsigned short h) {
    return __builtin_bit_cast(float, (unsigned)h << 16);
}
__device__ __forceinline__ unsigned f2u(float f) { return __builtin_bit_cast(unsigned, f); }
__device__ __forceinline__ float u2f(unsigned u) { return __builtin_bit_cast(float, u); }
__device__ __forceinline__ unsigned umin2(unsigned a, unsigned b) { return a < b ? a : b; }

union FragU { bf16x8 v; unsigned short u[8]; };

#define GLLOAD(gsrc, lbase)                                                              \
    __builtin_amdgcn_global_load_lds(                                                    \
        (const __attribute__((address_space(1))) unsigned int*)(gsrc),                   \
        (__attribute__((address_space(3))) unsigned int*)(lbase), 16, 0, 0)

// two f32 -> 2 fp8 e4m3 (bytes 0,1), negated / plain
__device__ __forceinline__ unsigned cvt8n(float a, float b) {
    unsigned r;
    asm("v_cvt_pk_fp8_f32 %0, -%1, -%2" : "=v"(r) : "v"(a), "v"(b));
    return r;
}
__device__ __forceinline__ unsigned cvt8(float a, float b) {
    unsigned r;
    asm("v_cvt_pk_fp8_f32 %0, %1, %2" : "=v"(r) : "v"(a), "v"(b));
    return r;
}

// ---------------- prep: cb -> fp8(256x, chunk-tiled) + cnh2 ----------------
__global__ __launch_bounds__(256) void prep(const float* __restrict__ cb,
                                            char* __restrict__ cbb8,
                                            unsigned* __restrict__ cnh2) {
    const int k = blockIdx.x * 4 + (threadIdx.x >> 6);
    const int lane = threadIdx.x & 63;
    float4 v = *reinterpret_cast<const float4*>(cb + (size_t)k * DIM + lane * 4);
    float s = v.x * v.x + v.y * v.y + v.z * v.z + v.w * v.w;
    #pragma unroll
    for (int off = 32; off; off >>= 1) s += __shfl_down(s, off);
    if (lane == 0) {
        float cn = 128.0f + 128.0f * s;               // 128 + 128|e|^2
        unsigned short chi = f2bf(cn);
        unsigned short clo = f2bf(cn - bf2f(chi));
        cnh2[k] = (unsigned)chi | ((unsigned)clo << 16);
    }
    const unsigned wlo = cvt8(256.0f * v.x, 256.0f * v.y);
    const unsigned whi = cvt8(256.0f * v.z, 256.0f * v.w);
    const unsigned dw = __builtin_amdgcn_perm(whi, wlo, 0x05040100u);  // [b0,b1,B0,B1]
    const int d0 = lane * 4, rem = d0 & 31;
    const int byte = (k >> 5) * 8192 + ((rem >> 3) & 1) * 4096 + (d0 >> 5) * 512
                   + (k & 31) * 16 + ((rem & 7) + ((rem >> 4) << 3));
    *reinterpret_cast<unsigned*>(cbb8 + byte) = dw;
}

// ---------------- fused: fp8 argmin sweep + scatter + loss ----------------
// 512 blocks x 4 waves (2 tg x 2 kh), 64 tokens/wave. r10 skeleton; fp8 halves
// af bytes, staging bytes, and xf registers. af layout is conflict-free-linear
// (no swizzle): lane reads 16B at hi*4096 + q*512 + r*16 (contiguous 512B/group).
__global__ __launch_bounds__(256, 2) void vq_fused(const float* __restrict__ x,
                                                   const char* __restrict__ cbb8,
                                                   const unsigned* __restrict__ cnh2,
                                                   const float* __restrict__ cbf,
                                                   float* __restrict__ out,
                                                   float* __restrict__ part) {
    __shared__ __align__(16) char ring[32768];        // x-tile / 2x16KB dbuf / scatter
    __shared__ unsigned cnl[1024];
    __shared__ unsigned kbx[4][64];
    __shared__ int kkl[128];
    __shared__ float wsum[4];
    const int tid = threadIdx.x;
    const int w = tid >> 6, lane = tid & 63, hi = lane >> 5, ln31 = lane & 31;
    const int tg = w >> 1, kh = w & 1;
    const int tw0 = blockIdx.x * 128;
    const int b = tw0 >> 12, tb = tw0 & (T_LEN - 1);

    cnl[tid] = cnh2[tid];
    cnl[tid + 256] = cnh2[tid + 256];
    cnl[tid + 512] = cnh2[tid + 512];
    cnl[tid + 768] = cnh2[tid + 768];

    // ---- x ingest: [128 t][256 d] fp8 tile (32 KB), negated, d-bytes xor-swizzled ----
    const int tqi = tid & 31, cqi = tid >> 5;         // 32 t-quads x 8 c-octs
    const float* xb = x + (size_t)b * DIM * T_LEN + tb + 4 * tqi;
    float x2s = 0.0f;
    #pragma unroll
    for (int ii = 0; ii < 8; ++ii) {
        const int cl = (ii * 8 + cqi) * 4;            // dim quad 0..252
        const float* p = xb + (size_t)cl * T_LEN;
        const float4 P0 = *reinterpret_cast<const float4*>(p);
        const float4 P1 = *reinterpret_cast<const float4*>(p + T_LEN);
        const float4 P2 = *reinterpret_cast<const float4*>(p + 2 * T_LEN);
        const float4 P3 = *reinterpret_cast<const float4*>(p + 3 * T_LEN);
        x2s = fmaf(P0.x, P0.x, fmaf(P0.y, P0.y, fmaf(P0.z, P0.z, fmaf(P0.w, P0.w, x2s))));
        x2s = fmaf(P1.x, P1.x, fmaf(P1.y, P1.y, fmaf(P1.z, P1.z, fmaf(P1.w, P1.w, x2s))));
        x2s = fmaf(P2.x, P2.x, fmaf(P2.y, P2.y, fmaf(P2.z, P2.z, fmaf(P2.w, P2.w, x2s))));
        x2s = fmaf(P3.x, P3.x, fmaf(P3.y, P3.y, fmaf(P3.z, P3.z, fmaf(P3.w, P3.w, x2s))));
        const unsigned lo0 = cvt8n(P0.x, P0.y), hi0 = cvt8n(P0.z, P0.w);
        const unsigned lo1 = cvt8n(P1.x, P1.y), hi1 = cvt8n(P1.z, P1.w);
        const unsigned lo2 = cvt8n(P2.x, P2.y), hi2 = cvt8n(P2.z, P2.w);
        const unsigned lo3 = cvt8n(P3.x, P3.y), hi3 = cvt8n(P3.z, P3.w);
        const unsigned s01 = __builtin_amdgcn_perm(lo1, lo0, 0x05010400u);
        const unsigned s23 = __builtin_amdgcn_perm(lo3, lo2, 0x05010400u);
        const unsigned u01 = __builtin_amdgcn_perm(hi1, hi0, 0x05010400u);
        const unsigned u23 = __builtin_amdgcn_perm(hi3, hi2, 0x05010400u);
        const unsigned t0 = __builtin_amdgcn_perm(s23, s01, 0x05040100u);
        const unsigned t1 = __builtin_amdgcn_perm(s23, s01, 0x07060302u);
        const unsigned t2 = __builtin_amdgcn_perm(u23, u01, 0x05040100u);
        const unsigned t3 = __builtin_amdgcn_perm(u23, u01, 0x07060302u);
        const int ta = 4 * tqi;
        *reinterpret_cast<unsigned*>(ring + (ta + 0) * 256 + (cl ^ (((ta + 0) & 15) << 3))) = t0;
        *reinterpret_cast<unsigned*>(ring + (ta + 1) * 256 + (cl ^ (((ta + 1) & 15) << 3))) = t1;
        *reinterpret_cast<unsigned*>(ring + (ta + 2) * 256 + (cl ^ (((ta + 2) & 15) << 3))) = t2;
        *reinterpret_cast<unsigned*>(ring + (ta + 3) * 256 + (cl ^ (((ta + 3) & 15) << 3))) = t3;
    }
    __syncthreads();

    // ---- xf frags: B-operand fp8, lane = (token col = l&31, k = hi*8+j) ----
    long xf0[16], xf1[16];                            // 64 VGPR total
    {
        const int tp0 = tg * 64 + ln31, tp1 = tg * 64 + 32 + ln31;
        const int z0 = (tp0 & 15) << 3, z1 = (tp1 & 15) << 3;
        #pragma unroll
        for (int kb = 0; kb < 16; ++kb) {
            const int o = kb * 16 + hi * 8;
            xf0[kb] = *reinterpret_cast<const long*>(ring + tp0 * 256 + (o ^ z0));
            xf1[kb] = *reinterpret_cast<const long*>(ring + tp1 * 256 + (o ^ z1));
        }
    }
    __syncthreads();                                  // ring free for staging

    // ---- staging: chunks kc (kh0) and 16+kc (kh1) -> 16 KB, linear ----
    auto stage = [&](int kc, int buf) {
        char* lb = ring + buf * 16384 + w * 1024;
        const char* gc = cbb8 + kc * 8192;
        #pragma unroll
        for (int j = 0; j < 4; ++j) {
            const int o = j * 4096 + tid * 16;
            GLLOAD(gc + (o & 8191) + (o >> 13) * 131072, lb + j * 4096);
        }
    };
    stage(0, 0);

    FragU cfr0, onef;                                 // bf16 cn-fold operands
    #pragma unroll
    for (int i = 0; i < 8; ++i) onef.u[i] = (hi == 0 && i < 2) ? 0x3F80 : 0;

    unsigned b0a = 0xFFFFFFFFu, b0b = 0xFFFFFFFFu;
    unsigned b1a = 0xFFFFFFFFu, b1b = 0xFFFFFFFFu;

    for (int kc = 0; kc < 16; ++kc) {
        const int cur = kc & 1;
        if (kc < 15) {
            stage(kc + 1, cur ^ 1);
            asm volatile("s_waitcnt vmcnt(4)" ::: "memory");   // this round landed
        } else {
            asm volatile("s_waitcnt vmcnt(0)" ::: "memory");
        }
        __builtin_amdgcn_s_barrier();
        __builtin_amdgcn_sched_barrier(0);

        const unsigned d = cnl[kh * 512 + kc * 32 + ln31];
        #pragma unroll
        for (int i = 0; i < 8; ++i) cfr0.u[i] = 0;
        if (hi == 0) {
            cfr0.u[0] = (unsigned short)(d & 0xFFFFu);
            cfr0.u[1] = (unsigned short)(d >> 16);
        }

        f32x16 acc0, acc1;
        #pragma unroll
        for (int i = 0; i < 16; ++i) { acc0[i] = 0.0f; acc1[i] = 0.0f; }
        acc0 = __builtin_amdgcn_mfma_f32_32x32x16_bf16(cfr0.v, onef.v, acc0, 0, 0, 0);
        acc1 = __builtin_amdgcn_mfma_f32_32x32x16_bf16(cfr0.v, onef.v, acc1, 0, 0, 0);

        const char* cbp = ring + cur * 16384 + kh * 8192 + hi * 4096 + ln31 * 16;
        #pragma unroll
        for (int hb = 0; hb < 2; ++hb) {              // 2 batches of 4 x b128
            long2x aw[4];
            #pragma unroll
            for (int i = 0; i < 4; ++i)
                aw[i] = *reinterpret_cast<const long2x*>(cbp + (hb * 4 + i) * 512);
            #pragma unroll
            for (int i = 0; i < 4; ++i) {
                const int kb = (hb * 4 + i) * 2;
                acc0 = __builtin_amdgcn_mfma_f32_32x32x16_fp8_fp8(aw[i].x, xf0[kb], acc0, 0, 0, 0);
                acc1 = __builtin_amdgcn_mfma_f32_32x32x16_fp8_fp8(aw[i].x, xf1[kb], acc1, 0, 0, 0);
                acc0 = __builtin_amdgcn_mfma_f32_32x32x16_fp8_fp8(aw[i].y, xf0[kb + 1], acc0, 0, 0, 0);
                acc1 = __builtin_amdgcn_mfma_f32_32x32x16_fp8_fp8(aw[i].y, xf1[kb + 1], acc1, 0, 0, 0);
            }
        }

        const int kbl = kh * 512 + kc * 32 + hi * 4;
        #pragma unroll
        for (int rg = 0; rg < 16; ++rg) {
            const unsigned kk = (unsigned)(kbl + (rg & 3) + 8 * (rg >> 2));
            const unsigned p0 = (f2u(acc0[rg]) & 0xFFFFFC00u) | kk;
            const unsigned p1 = (f2u(acc1[rg]) & 0xFFFFFC00u) | kk;
            if (rg & 1) { b0b = umin2(b0b, p0); b1b = umin2(b1b, p1); }
            else        { b0a = umin2(b0a, p0); b1a = umin2(b1a, p1); }
        }
        __builtin_amdgcn_s_barrier();
        __builtin_amdgcn_sched_barrier(0);
    }

    // merge chains + hi-halves
    unsigned best0 = umin2(b0a, b0b);
    unsigned best1 = umin2(b1a, b1b);
    best0 = umin2(best0, __shfl_xor(best0, 32));
    best1 = umin2(best1, __shfl_xor(best1, 32));
    if (hi == 0) { kbx[w][ln31] = best0; kbx[w][32 + ln31] = best1; }
    __syncthreads();

    float red = x2s;
    if (kh == 0) {                    // merge K-halves; token = tw0 + tg*64 + lane
        const unsigned key = umin2(kbx[w][lane], kbx[w + 1][lane]);
        kkl[tg * 64 + lane] = (int)(key & 1023u);
        // per-token |e-x|^2 = (s'-128)/128 + |x|^2
        red += (u2f(key & 0xFFFFFC00u) - 128.0f) * 0.0078125f;
    }
    #pragma unroll
    for (int off = 32; off; off >>= 1) red += __shfl_down(red, off);
    if (lane == 0) wsum[w] = red;
    __syncthreads();
    if (tid == 0) part[blockIdx.x] = wsum[0] + wsum[1] + wsum[2] + wsum[3];

    // ---- fused scatter: 8 slices of 32 c through [32][132] f32 tile ----
    float* fs = (float*)ring;
    const int tt = tid & 127, ch = tid >> 7;
    const size_t rowb = (size_t)kkl[tt] * DIM;
    #pragma unroll 1
    for (int sl = 0; sl < 8; ++sl) {
        float4 g[4];
        #pragma unroll
        for (int i = 0; i < 4; ++i)
            g[i] = *reinterpret_cast<const float4*>(cbf + rowb + sl * 32 + ch * 16 + 4 * i);
        __syncthreads();
        #pragma unroll
        for (int i = 0; i < 4; ++i) {
            const int c0 = ch * 16 + 4 * i;
            fs[(c0 + 0) * 132 + tt] = g[i].x;
            fs[(c0 + 1) * 132 + tt] = g[i].y;
            fs[(c0 + 2) * 132 + tt] = g[i].z;
            fs[(c0 + 3) * 132 + tt] = g[i].w;
        }
        __syncthreads();
        #pragma unroll
        for (int p = 0; p < 4; ++p) {
            const int c = tid >> 3, tq = (tid & 7) + p * 8;
            const float4 v = *reinterpret_cast<const float4*>(fs + c * 132 + tq * 4);
            *reinterpret_cast<float4*>(
                out + (((size_t)(b * DIM + sl * 32 + c)) << 12) + tb + tq * 4) = v;
        }
    }
}

// ---------------- finalize loss ----------------
__global__ __launch_bounds__(256) void finalize(const float* __restrict__ part,
                                                float* __restrict__ loss_out) {
    double s = (double)part[threadIdx.x] + (double)part[threadIdx.x + 256];
    #pragma unroll
    for (int off = 32; off; off >>= 1) s += __shfl_down(s, off);
    __shared__ double wsum[4];
    const int lane = threadIdx.x & 63, wv = threadIdx.x >> 6;
    if (lane == 0) wsum[wv] = s;
    __syncthreads();
    if (threadIdx.x == 0)
        *loss_out = (float)(2.0 * (wsum[0] + wsum[1] + wsum[2] + wsum[3]) / (double)NELEM);
}

extern "C" void kernel_launch(void* const* d_in, const int* in_sizes, int n_in,
                              void* d_out, int out_size, void* d_ws, size_t ws_size,
                              hipStream_t stream) {
    const float* x  = (const float*)d_in[0];    // [16,256,4096]
    const float* cb = (const float*)d_in[1];    // [1024,256]
    float* out = (float*)d_out;                 // quant (16777216) + loss (1)
    unsigned* ws = (unsigned*)d_ws;
    unsigned* cnh2 = ws;                        // 1024 u32
    float* part = (float*)(ws + 1024);          // 512 f32
    char* cbb8 = (char*)(ws + 4096);            // 256 KB fp8 codebook (chunk-tiled)

    prep<<<K_CODES / 4, 256, 0, stream>>>(cb, cbb8, cnh2);
    vq_fused<<<N_TOK / 128, 256, 0, stream>>>(x, cbb8, cnh2, cb, out, part);
    finalize<<<1, 256, 0, stream>>>(part, out + NELEM);
}

// Round 14
// 49.416 us; speedup vs baseline: 3.1528x; 1.1605x over previous
//
#include <hip/hip_runtime.h>

#define DIM 256
#define T_LEN 4096
#define K_CODES 1024
#define N_TOK 65536
#define NELEM 16777216

// ws layout (32-bit units):
//   [0,1024)       cnh2[k] packed (bf16_hi | bf16_lo<<16) of 128 + 128*|e_k|^2
//   [1024,1536)    loss partials (512 f32)
//   [4096,69632)   cbb8: fp8(256*cb), MX-tiled 256 KB:
//                  byte = ci*8192 + wnd*2048 + hs*1024 + half*512 + r*16 + off
//                  code k = ci*32 + r; dim d: wnd=d>>6, dw=d&63, hs=dw>>5,
//                  i=dw&31, half=i>>4, off=i&15.
// Score: s' = 128 + 128|e|^2 - 256*(e_fp8 . x_fp8) in ~[80,180] > 0 (== r13 math;
// MX scales set to 1.0 so the dot is bit-identical fp8 arithmetic).

typedef __attribute__((ext_vector_type(8))) short bf16x8;
typedef __attribute__((ext_vector_type(16))) float f32x16;
typedef __attribute__((ext_vector_type(8))) int i32x8;

__device__ __forceinline__ unsigned short f2bf(float f) {     // RNE f32->bf16
    unsigned u = __builtin_bit_cast(unsigned, f);
    return (unsigned short)((u + 0x7FFFu + ((u >> 16) & 1u)) >> 16);
}
__device__ __forceinline__ float bf2f(unsigned short h) {
    return __builtin_bit_cast(float, (unsigned)h << 16);
}
__device__ __forceinline__ unsigned f2u(float f) { return __builtin_bit_cast(unsigned, f); }
__device__ __forceinline__ float u2f(unsigned u) { return __builtin_bit_cast(float, u); }
__device__ __forceinline__ unsigned umin2(unsigned a, unsigned b) { return a < b ? a : b; }

union FragU { bf16x8 v; unsigned short u[8]; };

#define GLLOAD(gsrc, lbase)                                                              \
    __builtin_amdgcn_global_load_lds(                                                    \
        (const __attribute__((address_space(1))) unsigned int*)(gsrc),                   \
        (__attribute__((address_space(3))) unsigned int*)(lbase), 16, 0, 0)

// two f32 -> 2 fp8 e4m3 (bytes 0,1), negated / plain
__device__ __forceinline__ unsigned cvt8n(float a, float b) {
    unsigned r;
    asm("v_cvt_pk_fp8_f32 %0, -%1, -%2" : "=v"(r) : "v"(a), "v"(b));
    return r;
}
__device__ __forceinline__ unsigned cvt8(float a, float b) {
    unsigned r;
    asm("v_cvt_pk_fp8_f32 %0, %1, %2" : "=v"(r) : "v"(a), "v"(b));
    return r;
}

// ---------------- prep: cb -> fp8(256x, MX-tiled) + cnh2 ----------------
__global__ __launch_bounds__(256) void prep(const float* __restrict__ cb,
                                            char* __restrict__ cbb8,
                                            unsigned* __restrict__ cnh2) {
    const int k = blockIdx.x * 4 + (threadIdx.x >> 6);
    const int lane = threadIdx.x & 63;
    float4 v = *reinterpret_cast<const float4*>(cb + (size_t)k * DIM + lane * 4);
    float s = v.x * v.x + v.y * v.y + v.z * v.z + v.w * v.w;
    #pragma unroll
    for (int off = 32; off; off >>= 1) s += __shfl_down(s, off);
    if (lane == 0) {
        float cn = 128.0f + 128.0f * s;               // 128 + 128|e|^2
        unsigned short chi = f2bf(cn);
        unsigned short clo = f2bf(cn - bf2f(chi));
        cnh2[k] = (unsigned)chi | ((unsigned)clo << 16);
    }
    const unsigned wlo = cvt8(256.0f * v.x, 256.0f * v.y);
    const unsigned whi = cvt8(256.0f * v.z, 256.0f * v.w);
    const unsigned dw = __builtin_amdgcn_perm(whi, wlo, 0x05040100u);  // [x,y,z,w]
    const int d0 = lane * 4;
    const int wnd = d0 >> 6, dwi = d0 & 63, hs = dwi >> 5, i = dwi & 31;
    const int byte = (k >> 5) * 8192 + wnd * 2048 + hs * 1024 + (i >> 4) * 512
                   + (k & 31) * 16 + (i & 15);
    *reinterpret_cast<unsigned*>(cbb8 + byte) = dw;
}

// ---------------- fused: MX-fp8 argmin sweep + scatter + loss ----------------
// r13 skeleton (512 blocks x 4 waves, 2tg x 2kh, 64 tok/wave, 16 rounds, counted
// vmcnt(4) + raw barriers, fused scatter). MFMA core swapped to
// mfma_scale_f32_32x32x64_f8f6f4 with unit scales: 10 MFMA/round (was 34).
__global__ __launch_bounds__(256, 2) void vq_fused(const float* __restrict__ x,
                                                   const char* __restrict__ cbb8,
                                                   const unsigned* __restrict__ cnh2,
                                                   const float* __restrict__ cbf,
                                                   float* __restrict__ out,
                                                   float* __restrict__ part) {
    __shared__ __align__(16) char ring[32768];        // x-tile / 2x16KB dbuf / scatter
    __shared__ unsigned cnl[1024];
    __shared__ unsigned kbx[4][64];
    __shared__ int kkl[128];
    __shared__ float wsum[4];
    const int tid = threadIdx.x;
    const int w = tid >> 6, lane = tid & 63, hi = lane >> 5, ln31 = lane & 31;
    const int tg = w >> 1, kh = w & 1;
    const int tw0 = blockIdx.x * 128;
    const int b = tw0 >> 12, tb = tw0 & (T_LEN - 1);

    cnl[tid] = cnh2[tid];
    cnl[tid + 256] = cnh2[tid + 256];
    cnl[tid + 512] = cnh2[tid + 512];
    cnl[tid + 768] = cnh2[tid + 768];

    // ---- x ingest: [128 t][256 d] fp8 tile (32 KB), negated, 8B-granule XOR ----
    const int tqi = tid & 31, cqi = tid >> 5;         // 32 t-quads x 8 c-octs
    const float* xb = x + (size_t)b * DIM * T_LEN + tb + 4 * tqi;
    float x2s = 0.0f;
    #pragma unroll
    for (int ii = 0; ii < 8; ++ii) {
        const int cl = (ii * 8 + cqi) * 4;            // dim quad 0..252
        const float* p = xb + (size_t)cl * T_LEN;
        const float4 P0 = *reinterpret_cast<const float4*>(p);
        const float4 P1 = *reinterpret_cast<const float4*>(p + T_LEN);
        const float4 P2 = *reinterpret_cast<const float4*>(p + 2 * T_LEN);
        const float4 P3 = *reinterpret_cast<const float4*>(p + 3 * T_LEN);
        x2s = fmaf(P0.x, P0.x, fmaf(P0.y, P0.y, fmaf(P0.z, P0.z, fmaf(P0.w, P0.w, x2s))));
        x2s = fmaf(P1.x, P1.x, fmaf(P1.y, P1.y, fmaf(P1.z, P1.z, fmaf(P1.w, P1.w, x2s))));
        x2s = fmaf(P2.x, P2.x, fmaf(P2.y, P2.y, fmaf(P2.z, P2.z, fmaf(P2.w, P2.w, x2s))));
        x2s = fmaf(P3.x, P3.x, fmaf(P3.y, P3.y, fmaf(P3.z, P3.z, fmaf(P3.w, P3.w, x2s))));
        const unsigned lo0 = cvt8n(P0.x, P0.y), hi0 = cvt8n(P0.z, P0.w);
        const unsigned lo1 = cvt8n(P1.x, P1.y), hi1 = cvt8n(P1.z, P1.w);
        const unsigned lo2 = cvt8n(P2.x, P2.y), hi2 = cvt8n(P2.z, P2.w);
        const unsigned lo3 = cvt8n(P3.x, P3.y), hi3 = cvt8n(P3.z, P3.w);
        const unsigned s01 = __builtin_amdgcn_perm(lo1, lo0, 0x05010400u);
        const unsigned s23 = __builtin_amdgcn_perm(lo3, lo2, 0x05010400u);
        const unsigned u01 = __builtin_amdgcn_perm(hi1, hi0, 0x05010400u);
        const unsigned u23 = __builtin_amdgcn_perm(hi3, hi2, 0x05010400u);
        const unsigned t0 = __builtin_amdgcn_perm(s23, s01, 0x05040100u);
        const unsigned t1 = __builtin_amdgcn_perm(s23, s01, 0x07060302u);
        const unsigned t2 = __builtin_amdgcn_perm(u23, u01, 0x05040100u);
        const unsigned t3 = __builtin_amdgcn_perm(u23, u01, 0x07060302u);
        const int ta = 4 * tqi;
        *reinterpret_cast<unsigned*>(ring + (ta + 0) * 256 + (cl ^ (((ta + 0) & 15) << 3))) = t0;
        *reinterpret_cast<unsigned*>(ring + (ta + 1) * 256 + (cl ^ (((ta + 1) & 15) << 3))) = t1;
        *reinterpret_cast<unsigned*>(ring + (ta + 2) * 256 + (cl ^ (((ta + 2) & 15) << 3))) = t2;
        *reinterpret_cast<unsigned*>(ring + (ta + 3) * 256 + (cl ^ (((ta + 3) & 15) << 3))) = t3;
    }
    __syncthreads();

    // ---- xf frags: B-operand, 4 K-windows of 64; lane = (token=l&31, k=(l>>5)*32+i) ----
    i32x8 xf0[4], xf1[4];                             // 64 VGPR total
    {
        const int tp0 = tg * 64 + ln31, tp1 = tg * 64 + 32 + ln31;
        const int z0 = (tp0 & 15) << 3, z1 = (tp1 & 15) << 3;
        #pragma unroll
        for (int wnd = 0; wnd < 4; ++wnd) {
            #pragma unroll
            for (int g = 0; g < 4; ++g) {
                const int o = wnd * 64 + hi * 32 + g * 8;
                const long v0 = *reinterpret_cast<const long*>(ring + tp0 * 256 + (o ^ z0));
                const long v1 = *reinterpret_cast<const long*>(ring + tp1 * 256 + (o ^ z1));
                xf0[wnd][2 * g] = (int)(unsigned)(v0 & 0xFFFFFFFFu);
                xf0[wnd][2 * g + 1] = (int)(unsigned)(((unsigned long)v0) >> 32);
                xf1[wnd][2 * g] = (int)(unsigned)(v1 & 0xFFFFFFFFu);
                xf1[wnd][2 * g + 1] = (int)(unsigned)(((unsigned long)v1) >> 32);
            }
        }
    }
    __syncthreads();                                  // ring free for staging

    // ---- staging: chunks kc (kh0) and 16+kc (kh1) -> 16 KB, linear copy ----
    auto stage = [&](int kc, int buf) {
        char* lb = ring + buf * 16384 + w * 1024;
        const char* gc = cbb8 + kc * 8192;
        #pragma unroll
        for (int j = 0; j < 4; ++j) {
            const int o = j * 4096 + tid * 16;
            GLLOAD(gc + (o & 8191) + (o >> 13) * 131072, lb + j * 4096);
        }
    };
    stage(0, 0);

    FragU cfr0, onef;                                 // bf16 cn-fold operands
    #pragma unroll
    for (int i = 0; i < 8; ++i) onef.u[i] = (hi == 0 && i < 2) ? 0x3F80 : 0;

    unsigned b0a = 0xFFFFFFFFu, b0b = 0xFFFFFFFFu;
    unsigned b1a = 0xFFFFFFFFu, b1b = 0xFFFFFFFFu;

    for (int kc = 0; kc < 16; ++kc) {
        const int cur = kc & 1;
        if (kc < 15) {
            stage(kc + 1, cur ^ 1);
            asm volatile("s_waitcnt vmcnt(4)" ::: "memory");   // this round landed
        } else {
            asm volatile("s_waitcnt vmcnt(0)" ::: "memory");
        }
        __builtin_amdgcn_s_barrier();
        __builtin_amdgcn_sched_barrier(0);

        const unsigned d = cnl[kh * 512 + kc * 32 + ln31];
        #pragma unroll
        for (int i = 0; i < 8; ++i) cfr0.u[i] = 0;
        if (hi == 0) {
            cfr0.u[0] = (unsigned short)(d & 0xFFFFu);
            cfr0.u[1] = (unsigned short)(d >> 16);
        }

        f32x16 acc0, acc1;
        #pragma unroll
        for (int i = 0; i < 16; ++i) { acc0[i] = 0.0f; acc1[i] = 0.0f; }
        acc0 = __builtin_amdgcn_mfma_f32_32x32x16_bf16(cfr0.v, onef.v, acc0, 0, 0, 0);
        acc1 = __builtin_amdgcn_mfma_f32_32x32x16_bf16(cfr0.v, onef.v, acc1, 0, 0, 0);

        // A frags: per window 2 contiguous-512B b128 reads (conflict-free)
        const char* cbpA = ring + cur * 16384 + kh * 8192 + hi * 1024 + ln31 * 16;
        #pragma unroll
        for (int wnd = 0; wnd < 4; ++wnd) {
            const uint4 alo = *reinterpret_cast<const uint4*>(cbpA + wnd * 2048);
            const uint4 ahi = *reinterpret_cast<const uint4*>(cbpA + wnd * 2048 + 512);
            i32x8 aw;
            aw[0] = (int)alo.x; aw[1] = (int)alo.y; aw[2] = (int)alo.z; aw[3] = (int)alo.w;
            aw[4] = (int)ahi.x; aw[5] = (int)ahi.y; aw[6] = (int)ahi.z; aw[7] = (int)ahi.w;
            acc0 = __builtin_amdgcn_mfma_scale_f32_32x32x64_f8f6f4(
                aw, xf0[wnd], acc0, 0, 0, 0, 0x7F7F7F7F, 0, 0x7F7F7F7F);
            acc1 = __builtin_amdgcn_mfma_scale_f32_32x32x64_f8f6f4(
                aw, xf1[wnd], acc1, 0, 0, 0, 0x7F7F7F7F, 0, 0x7F7F7F7F);
        }

        const int kbl = kh * 512 + kc * 32 + hi * 4;
        #pragma unroll
        for (int rg = 0; rg < 16; ++rg) {
            const unsigned kk = (unsigned)(kbl + (rg & 3) + 8 * (rg >> 2));
            const unsigned p0 = (f2u(acc0[rg]) & 0xFFFFFC00u) | kk;
            const unsigned p1 = (f2u(acc1[rg]) & 0xFFFFFC00u) | kk;
            if (rg & 1) { b0b = umin2(b0b, p0); b1b = umin2(b1b, p1); }
            else        { b0a = umin2(b0a, p0); b1a = umin2(b1a, p1); }
        }
        __builtin_amdgcn_s_barrier();
        __builtin_amdgcn_sched_barrier(0);
    }

    // merge chains + hi-halves
    unsigned best0 = umin2(b0a, b0b);
    unsigned best1 = umin2(b1a, b1b);
    best0 = umin2(best0, __shfl_xor(best0, 32));
    best1 = umin2(best1, __shfl_xor(best1, 32));
    if (hi == 0) { kbx[w][ln31] = best0; kbx[w][32 + ln31] = best1; }
    __syncthreads();

    float red = x2s;
    if (kh == 0) {                    // merge K-halves; token = tw0 + tg*64 + lane
        const unsigned key = umin2(kbx[w][lane], kbx[w + 1][lane]);
        kkl[tg * 64 + lane] = (int)(key & 1023u);
        red += (u2f(key & 0xFFFFFC00u) - 128.0f) * 0.0078125f;
    }
    #pragma unroll
    for (int off = 32; off; off >>= 1) red += __shfl_down(red, off);
    if (lane == 0) wsum[w] = red;
    __syncthreads();
    if (tid == 0) part[blockIdx.x] = wsum[0] + wsum[1] + wsum[2] + wsum[3];

    // ---- fused scatter: 8 slices of 32 c through [32][132] f32 tile ----
    float* fs = (float*)ring;
    const int tt = tid & 127, ch = tid >> 7;
    const size_t rowb = (size_t)kkl[tt] * DIM;
    #pragma unroll 1
    for (int sl = 0; sl < 8; ++sl) {
        float4 g[4];
        #pragma unroll
        for (int i = 0; i < 4; ++i)
            g[i] = *reinterpret_cast<const float4*>(cbf + rowb + sl * 32 + ch * 16 + 4 * i);
        __syncthreads();
        #pragma unroll
        for (int i = 0; i < 4; ++i) {
            const int c0 = ch * 16 + 4 * i;
            fs[(c0 + 0) * 132 + tt] = g[i].x;
            fs[(c0 + 1) * 132 + tt] = g[i].y;
            fs[(c0 + 2) * 132 + tt] = g[i].z;
            fs[(c0 + 3) * 132 + tt] = g[i].w;
        }
        __syncthreads();
        #pragma unroll
        for (int p = 0; p < 4; ++p) {
            const int c = tid >> 3, tq = (tid & 7) + p * 8;
            const float4 v = *reinterpret_cast<const float4*>(fs + c * 132 + tq * 4);
            *reinterpret_cast<float4*>(
                out + (((size_t)(b * DIM + sl * 32 + c)) << 12) + tb + tq * 4) = v;
        }
    }
}

// ---------------- finalize loss ----------------
__global__ __launch_bounds__(256) void finalize(const float* __restrict__ part,
                                                float* __restrict__ loss_out) {
    double s = (double)part[threadIdx.x] + (double)part[threadIdx.x + 256];
    #pragma unroll
    for (int off = 32; off; off >>= 1) s += __shfl_down(s, off);
    __shared__ double wsum[4];
    const int lane = threadIdx.x & 63, wv = threadIdx.x >> 6;
    if (lane == 0) wsum[wv] = s;
    __syncthreads();
    if (threadIdx.x == 0)
        *loss_out = (float)(2.0 * (wsum[0] + wsum[1] + wsum[2] + wsum[3]) / (double)NELEM);
}

extern "C" void kernel_launch(void* const* d_in, const int* in_sizes, int n_in,
                              void* d_out, int out_size, void* d_ws, size_t ws_size,
                              hipStream_t stream) {
    const float* x  = (const float*)d_in[0];    // [16,256,4096]
    const float* cb = (const float*)d_in[1];    // [1024,256]
    float* out = (float*)d_out;                 // quant (16777216) + loss (1)
    unsigned* ws = (unsigned*)d_ws;
    unsigned* cnh2 = ws;                        // 1024 u32
    float* part = (float*)(ws + 1024);          // 512 f32
    char* cbb8 = (char*)(ws + 4096);            // 256 KB fp8 codebook (MX-tiled)

    prep<<<K_CODES / 4, 256, 0, stream>>>(cb, cbb8, cnh2);
    vq_fused<<<N_TOK / 128, 256, 0, stream>>>(x, cbb8, cnh2, cb, out, part);
    finalize<<<1, 256, 0, stream>>>(part, out + NELEM);
}